// Round 1
// baseline (245.826 us; speedup 1.0000x reference)
//
#include <hip/hip_runtime.h>

#define BOUND 1e-6f
#define HALF_PI 1.57079632679489662f

// One wave (64 lanes) per row of 256 elements; lane handles 4 contiguous
// elements via an aligned float4 load (row stride = 1024 B).
// out[j] = radius * prod_{i<j}(sin(a_i)+B) * (cos(a_j)+B),  j < 256
// out[256] = radius * prod_{i<256}(sin(a_i)+B)
__global__ __launch_bounds__(256) void spherize_kernel(
    const float* __restrict__ x,
    const float* __restrict__ p_phiL,
    const float* __restrict__ p_radius,
    const float* __restrict__ p_scaling,
    float* __restrict__ out,
    int n_rows)
{
    const float phi_L   = p_phiL[0];
    const float radius  = p_radius[0];
    const float scaling = p_scaling[0];
    const float amp     = HALF_PI - phi_L;

    const int lane            = threadIdx.x & 63;
    const int wave_in_block   = threadIdx.x >> 6;
    const int waves_per_block = blockDim.x >> 6;
    const int total_waves     = gridDim.x * waves_per_block;

    for (int row = blockIdx.x * waves_per_block + wave_in_block;
         row < n_rows; row += total_waves)
    {
        const float4 xv =
            *reinterpret_cast<const float4*>(x + (size_t)row * 256 + lane * 4);
        const float* xp = &xv.x;

        float s[4], c[4];
        #pragma unroll
        for (int k = 0; k < 4; ++k) {
            // sigmoid via hw exp + hw rcp (1-ulp): plenty accurate vs 6.4e-3 thr
            float e  = __expf(-scaling * xp[k]);
            float sg = __builtin_amdgcn_rcpf(1.0f + e);
            float a  = fmaf(amp, sg, phi_L);   // a in [phi_L, pi/2)
            s[k] = __sinf(a) + BOUND;
            c[k] = __cosf(a) + BOUND;
        }

        // intra-lane prefix products (exclusive per element)
        float q1 = s[0];
        float q2 = q1 * s[1];
        float q3 = q2 * s[2];
        float t  = q3 * s[3];          // lane-local total

        // inclusive multiplicative wave scan of t over 64 lanes
        float scan = t;
        #pragma unroll
        for (int off = 1; off < 64; off <<= 1) {
            float o = __shfl_up(scan, off, 64);
            if (lane >= off) scan *= o;
        }
        float excl = __shfl_up(scan, 1, 64);   // product of all lanes < me
        float base = radius * ((lane == 0) ? 1.0f : excl);

        float* orow = out + (size_t)row * 257 + lane * 4;
        orow[0] = base * c[0];
        orow[1] = base * q1 * c[1];
        orow[2] = base * q2 * c[2];
        orow[3] = base * q3 * c[3];
        if (lane == 63)
            out[(size_t)row * 257 + 256] = radius * scan;  // full product
    }
}

extern "C" void kernel_launch(void* const* d_in, const int* in_sizes, int n_in,
                              void* d_out, int out_size, void* d_ws, size_t ws_size,
                              hipStream_t stream) {
    // inputs: 0=x [N,256], 1=W_theta, 2=W_phi, 3=b_phi, 4=phi_L, 5=radius, 6=scaling
    const float* x         = (const float*)d_in[0];
    const float* p_phiL    = (const float*)d_in[4];
    const float* p_radius  = (const float*)d_in[5];
    const float* p_scaling = (const float*)d_in[6];
    float* out = (float*)d_out;

    const int n_rows = in_sizes[0] / 256;
    const int waves_per_block = 256 / 64;
    int blocks = (n_rows + waves_per_block - 1) / waves_per_block;
    if (blocks > 4096) blocks = 4096;   // grid-stride the rest

    spherize_kernel<<<blocks, 256, 0, stream>>>(x, p_phiL, p_radius, p_scaling,
                                                out, n_rows);
}

// Round 2
// 244.183 us; speedup vs baseline: 1.0067x; 1.0067x over previous
//
#include <hip/hip_runtime.h>

#define BOUND 1e-6f
#define HALF_PI 1.57079632679489662f

// DPP helper: masked/out-of-range lanes receive `oldv` (we pass 1.0f, the
// multiplicative identity). ctrl/row_mask must be literal constants.
#define UPD_DPP(oldv, srcv, ctrl, rmask)                                        \
  __int_as_float(__builtin_amdgcn_update_dpp(                                   \
      __float_as_int(oldv), __float_as_int(srcv), (ctrl), (rmask), 0xF, false))

// Inclusive multiplicative scan across the 64-lane wave, pure VALU (no DS):
// row_shr:1/2/4/8 within 16-lane rows, then row_bcast15 (rows 1,3) and
// row_bcast31 (rows 2,3). Lanes with invalid sources multiply by 1.0.
__device__ __forceinline__ float wave_incl_prod(float x) {
    x *= UPD_DPP(1.0f, x, 0x111, 0xF);  // row_shr:1
    x *= UPD_DPP(1.0f, x, 0x112, 0xF);  // row_shr:2
    x *= UPD_DPP(1.0f, x, 0x114, 0xF);  // row_shr:4
    x *= UPD_DPP(1.0f, x, 0x118, 0xF);  // row_shr:8
    x *= UPD_DPP(1.0f, x, 0x142, 0xA);  // row_bcast:15 -> rows 1,3
    x *= UPD_DPP(1.0f, x, 0x143, 0xC);  // row_bcast:31 -> rows 2,3
    return x;
}

// One wave per row of 256 elements. Lane l owns columns {l, 64+l, 128+l, 192+l}
// so ALL global loads and stores are lane-consecutive dwords (256B/instr,
// fully coalesced) -- the [N,257] output row stride (1028 B) forbids aligned
// vector stores on odd rows, so coalesced dword stores are optimal here.
// out[j]   = radius * prod_{i<j}(sin(a_i)+B) * (cos(a_j)+B),  j < 256
// out[256] = radius * prod_{i<256}(sin(a_i)+B)
__global__ __launch_bounds__(256) void spherize_kernel(
    const float* __restrict__ x,
    const float* __restrict__ p_phiL,
    const float* __restrict__ p_radius,
    const float* __restrict__ p_scaling,
    float* __restrict__ out,
    int n_rows)
{
    const float phi_L   = p_phiL[0];
    const float radius  = p_radius[0];
    const float scaling = p_scaling[0];
    const float amp     = HALF_PI - phi_L;

    const int lane            = threadIdx.x & 63;
    const int wave_in_block   = threadIdx.x >> 6;
    const int waves_per_block = blockDim.x >> 6;
    const int total_waves     = gridDim.x * waves_per_block;

    for (int row = blockIdx.x * waves_per_block + wave_in_block;
         row < n_rows; row += total_waves)
    {
        const float* xr = x + (size_t)row * 256 + lane;
        float xv[4];
        #pragma unroll
        for (int k = 0; k < 4; ++k) xv[k] = xr[k * 64];   // 4 x 256B coalesced

        float s[4], c[4];
        #pragma unroll
        for (int k = 0; k < 4; ++k) {
            float e  = __expf(-scaling * xv[k]);
            float sg = __builtin_amdgcn_rcpf(1.0f + e);
            float a  = fmaf(amp, sg, phi_L);   // a in [phi_L, pi/2)
            s[k] = __sinf(a) + BOUND;          // s in [~0.947, 1+1e-6]
            c[k] = __cosf(a) + BOUND;
        }

        // 4 independent segment scans (ILP), all in VALU
        float incl[4];
        #pragma unroll
        for (int k = 0; k < 4; ++k) incl[k] = wave_incl_prod(s[k]);

        // segment totals (uniform) and cumulative bases
        float U = radius;                      // radius * prod of segments < k
        float* orow = out + (size_t)row * 257 + lane;
        #pragma unroll
        for (int k = 0; k < 4; ++k) {
            // exclusive prefix within segment: incl / s  (s >= 0.947, rcp ~1ulp)
            float excl = incl[k] * __builtin_amdgcn_rcpf(s[k]);
            orow[64 * k] = U * excl * c[k];    // coalesced dword store
            float T = __int_as_float(
                __builtin_amdgcn_readlane(__float_as_int(incl[k]), 63));
            U *= T;
        }
        if (lane == 63)
            out[(size_t)row * 257 + 256] = U;  // radius * full product
    }
}

extern "C" void kernel_launch(void* const* d_in, const int* in_sizes, int n_in,
                              void* d_out, int out_size, void* d_ws, size_t ws_size,
                              hipStream_t stream) {
    // inputs: 0=x [N,256], 1=W_theta, 2=W_phi, 3=b_phi, 4=phi_L, 5=radius, 6=scaling
    const float* x         = (const float*)d_in[0];
    const float* p_phiL    = (const float*)d_in[4];
    const float* p_radius  = (const float*)d_in[5];
    const float* p_scaling = (const float*)d_in[6];
    float* out = (float*)d_out;

    const int n_rows = in_sizes[0] / 256;
    const int waves_per_block = 256 / 64;
    int blocks = (n_rows + waves_per_block - 1) / waves_per_block;
    if (blocks > 4096) blocks = 4096;   // grid-stride the rest

    spherize_kernel<<<blocks, 256, 0, stream>>>(x, p_phiL, p_radius, p_scaling,
                                                out, n_rows);
}